// Round 2
// baseline (153.791 us; speedup 1.0000x reference)
//
#include <hip/hip_runtime.h>

// KnowledgeEmbedding loss via bf16 MFMA GEMM, single phase.
// R13 (resubmit; prior round was an infra failure, kernel never ran):
// occupancy attack. Tile 64 rows x 128 negs, PITCH=104 shorts (13 chunks,
// K=104 stored; k=104..127 synthesized as zero-B fragments in registers).
// LDS 39 KB -> 4 blocks/CU (vs 2), grid 1024 = 4/CU, 16 waves/CU.
// 52-dword row stride is odd mod 32 banks -> naturally conflict-free b128
// reads/writes (XOR swizzle removed). rel = bid&7 -> XCD-affine (per-rel
// ~3.3MB working set fits one XCD's 4MB L2). Pos term spread 4 threads/row
// across both negblocks (3-4 chunk deep chains instead of 13).
// Bias folded at k=100 (A=bias, B=1.0) -> layout-agnostic softplus-sum.

#define EMBED   100
#define BATCH   4096
#define NUM_NEG 256
#define BM      64
#define BN      128
#define PITCH   104   // shorts per row = 13 chunks * 8 = 208 B = 52 dwords

typedef __attribute__((ext_vector_type(8))) short s8;
typedef __attribute__((ext_vector_type(4))) float f4;

struct RelP {
    const float* head;
    const float* tail;
    const float* bias;
    int hc, tc;
};

struct Params {
    RelP rel[8];
    const float* rel_vecs;
    const int*   batch_idxs;
    const int*   neg_idxs;
    float*       out;
};

__device__ __forceinline__ float softplus_f(float x) {
    float e = __expf(-fabsf(x));
    return fmaxf(x, 0.0f) + __logf(1.0f + e);
}

__device__ __forceinline__ unsigned short bf16_rne(float f) {
    unsigned u = __float_as_uint(f);
    u += 0x7FFFu + ((u >> 16) & 1u);
    return (unsigned short)(u >> 16);
}

__device__ __forceinline__ float bf16_to_f(short s) {
    return __uint_as_float(((unsigned)(unsigned short)s) << 16);
}

__device__ __forceinline__ s8 pack8(float4 f0, float4 f1) {
    s8 v = { (short)bf16_rne(f0.x), (short)bf16_rne(f0.y),
             (short)bf16_rne(f0.z), (short)bf16_rne(f0.w),
             (short)bf16_rne(f1.x), (short)bf16_rne(f1.y),
             (short)bf16_rne(f1.z), (short)bf16_rne(f1.w) };
    return v;
}

__launch_bounds__(256, 4)
__global__ void ke_kernel(Params p) {
    // grid: 1024. bid&7 = rel (XCD-affine under %8 round-robin dispatch).
    const int bid = blockIdx.x;
    const int r   = bid & 7;
    const int x   = bid >> 3;
    const int rb  = x & 63;              // rowblock 0..63 (64 rows each)
    const int nb  = x >> 6;              // negblock 0..1 (128 negs each)
    const int tid = threadIdx.x;

    __shared__ __align__(16) short As[BM * PITCH];   // 13312 B
    __shared__ __align__(16) short Bs[BN * PITCH];   // 26624 B -> total 39 KB

    const RelP rp = p.rel[r];

    // ---- staging: wave0 = A rows (64), waves1-2 = B rows (128) ----
    if (tid < BM) {
        const int row  = tid;
        const int grow = rb * BM + row;
        const int h  = p.batch_idxs[grow * 8 + rp.hc];
        const int ti = p.batch_idxs[grow * 8 + rp.tc];
        const float4* s4p = (const float4*)(rp.head + (size_t)h * EMBED);
        const float4* rv4 = (const float4*)(p.rel_vecs + r * EMBED);
        const unsigned short extra = bf16_rne(rp.bias[ti]);
        short* dst = As + row * PITCH;
#pragma unroll
        for (int c = 0; c < 12; ++c) {   // chunks 0..11 = floats 0..95
            float4 f0 = s4p[2 * c];
            float4 f1 = s4p[2 * c + 1];
            const float4 a = rv4[2 * c];
            const float4 b = rv4[2 * c + 1];
            f0.x += a.x; f0.y += a.y; f0.z += a.z; f0.w += a.w;
            f1.x += b.x; f1.y += b.y; f1.z += b.z; f1.w += b.w;
            *(s8*)(dst + 8 * c) = pack8(f0, f1);
        }
        {   // chunk 12: floats 96..99, bias at k=100, zeros 101..103
            float4 f = s4p[24];
            const float4 a = rv4[24];
            f.x += a.x; f.y += a.y; f.z += a.z; f.w += a.w;
            s8 v = { (short)bf16_rne(f.x), (short)bf16_rne(f.y),
                     (short)bf16_rne(f.z), (short)bf16_rne(f.w),
                     (short)extra, 0, 0, 0 };
            *(s8*)(dst + 96) = v;
        }
    } else if (tid < 192) {
        const int row = tid - 64;        // 0..127
        const int n = p.neg_idxs[r * NUM_NEG + nb * BN + row];
        const float4* s4p = (const float4*)(rp.tail + (size_t)n * EMBED);
        short* dst = Bs + row * PITCH;
#pragma unroll
        for (int c = 0; c < 12; ++c) {
            float4 f0 = s4p[2 * c];
            float4 f1 = s4p[2 * c + 1];
            *(s8*)(dst + 8 * c) = pack8(f0, f1);
        }
        {   // chunk 12: floats 96..99, 1.0 at k=100 (bias passthrough)
            float4 f = s4p[24];
            s8 v = { (short)bf16_rne(f.x), (short)bf16_rne(f.y),
                     (short)bf16_rne(f.z), (short)bf16_rne(f.w),
                     (short)0x3F80, 0, 0, 0 };
            *(s8*)(dst + 96) = v;
        }
    }

    // pos-term prep (idx/bias loads issued before barrier): threads 128..255,
    // 4 threads per pos row, 32 rows per block (both nb blocks participate).
    const bool doPos = tid >= 128;
    const float* ptail = rp.tail;
    float pbias = 0.0f;
    if (doPos) {
        const int pl   = tid - 128;      // 0..127
        const int prow = rb * BM + nb * 32 + (pl >> 2);
        const int pt   = p.batch_idxs[prow * 8 + rp.tc];
        ptail = rp.tail + (size_t)pt * EMBED;
        pbias = rp.bias[pt];
    }

    __syncthreads();

    // ---- MFMA: 4 waves as 2x2, wave tile 32 rows x 64 negs ----
    const int wave = tid >> 6;
    const int lane = tid & 63;
    const int li   = lane & 15;
    const int q    = lane >> 4;
    const int wm   = wave >> 1;          // row half (32 rows)
    const int wn   = wave & 1;           // neg half (64 negs)

    f4 acc[2][4];
#pragma unroll
    for (int i = 0; i < 2; ++i)
#pragma unroll
        for (int j = 0; j < 4; ++j)
            acc[i][j] = (f4){0.f, 0.f, 0.f, 0.f};

    const short* Ab = As + (wm * 32 + li) * PITCH;
    const short* Bb = Bs + (wn * 64 + li) * PITCH;

#pragma unroll
    for (int s = 0; s < 3; ++s) {        // k = 0..95, chunks q+4s all real
        const int co = 8 * (q + 4 * s);
        s8 a[2], b[4];
        a[0] = *(const s8*)(Ab + co);
        a[1] = *(const s8*)(Ab + 16 * PITCH + co);
        b[0] = *(const s8*)(Bb + co);
        b[1] = *(const s8*)(Bb + 16 * PITCH + co);
        b[2] = *(const s8*)(Bb + 32 * PITCH + co);
        b[3] = *(const s8*)(Bb + 48 * PITCH + co);
#pragma unroll
        for (int i = 0; i < 2; ++i)
#pragma unroll
            for (int j = 0; j < 4; ++j)
                acc[i][j] = __builtin_amdgcn_mfma_f32_16x16x32_bf16(a[i], b[j], acc[i][j], 0, 0, 0);
    }
    {   // s=3: k=96..127. Only q==0 (chunk 12) is real; q>=1 k-slices are zero.
        // All lanes read chunk 12 (broadcast, conflict-free); zero the B side
        // for q>=1 so garbage A contributes 0 exactly.
        const s8 z = {0, 0, 0, 0, 0, 0, 0, 0};
        s8 a[2], b[4];
        a[0] = *(const s8*)(Ab + 96);
        a[1] = *(const s8*)(Ab + 16 * PITCH + 96);
        b[0] = *(const s8*)(Bb + 96);
        b[1] = *(const s8*)(Bb + 16 * PITCH + 96);
        b[2] = *(const s8*)(Bb + 32 * PITCH + 96);
        b[3] = *(const s8*)(Bb + 48 * PITCH + 96);
        b[0] = q ? z : b[0];
        b[1] = q ? z : b[1];
        b[2] = q ? z : b[2];
        b[3] = q ? z : b[3];
#pragma unroll
        for (int i = 0; i < 2; ++i)
#pragma unroll
            for (int j = 0; j < 4; ++j)
                acc[i][j] = __builtin_amdgcn_mfma_f32_16x16x32_bf16(a[i], b[j], acc[i][j], 0, 0, 0);
    }

    // ---- epilogue: softplus-sum (bias folded into acc, layout-agnostic) ----
    float local = 0.0f;
#pragma unroll
    for (int i = 0; i < 2; ++i)
#pragma unroll
        for (int j = 0; j < 4; ++j) {
            local += softplus_f(acc[i][j].x);
            local += softplus_f(acc[i][j].y);
            local += softplus_f(acc[i][j].z);
            local += softplus_f(acc[i][j].w);
        }

    // ---- positive term: 4 threads per row, 3 chunks each (+chunk12 on part3) ----
    if (doPos) {
        const int pl   = tid - 128;
        const int prl  = pl >> 2;        // 0..31
        const int part = pl & 3;
        const short* exr = As + (nb * 32 + prl) * PITCH;
        const float4* tv = (const float4*)ptail;
        float d0 = 0.f, d1 = 0.f, d2 = 0.f, d3 = 0.f;
        const int cbase = 3 * part;      // parts cover chunks {0-2,3-5,6-8,9-11}
#pragma unroll
        for (int k = 0; k < 3; ++k) {
            const int c = cbase + k;
            const s8 e = *(const s8*)(exr + 8 * c);
            const float4 t0 = tv[2 * c];
            const float4 t1 = tv[2 * c + 1];
            d0 = fmaf(bf16_to_f(e[0]), t0.x, d0);
            d1 = fmaf(bf16_to_f(e[1]), t0.y, d1);
            d2 = fmaf(bf16_to_f(e[2]), t0.z, d2);
            d3 = fmaf(bf16_to_f(e[3]), t0.w, d3);
            d0 = fmaf(bf16_to_f(e[4]), t1.x, d0);
            d1 = fmaf(bf16_to_f(e[5]), t1.y, d1);
            d2 = fmaf(bf16_to_f(e[6]), t1.z, d2);
            d3 = fmaf(bf16_to_f(e[7]), t1.w, d3);
        }
        if (part == 3) {                 // chunk 12: floats 96..99
            const s8 e = *(const s8*)(exr + 96);
            const float4 t0 = tv[24];
            d0 = fmaf(bf16_to_f(e[0]), t0.x, d0);
            d1 = fmaf(bf16_to_f(e[1]), t0.y, d1);
            d2 = fmaf(bf16_to_f(e[2]), t0.z, d2);
            d3 = fmaf(bf16_to_f(e[3]), t0.w, d3);
        }
        float d = (d0 + d1) + (d2 + d3);
        d += __shfl_xor(d, 1, 64);
        d += __shfl_xor(d, 2, 64);       // 4-lane group now holds full dot
        if (part == 0) local += softplus_f(-(d + pbias));
    }

    // ---- reduction ----
#pragma unroll
    for (int off = 32; off > 0; off >>= 1)
        local += __shfl_down(local, off, 64);

    __syncthreads();                     // all As/Bs reads done -> safe to alias
    float* wsum = (float*)Bs;
    if ((tid & 63) == 0) wsum[tid >> 6] = local;
    __syncthreads();
    if (tid == 0) {
        const float s = (wsum[0] + wsum[1]) + (wsum[2] + wsum[3]);
        atomicAdd(p.out, s * (1.0f / BATCH));
    }
}

extern "C" void kernel_launch(void* const* d_in, const int* in_sizes, int n_in,
                              void* d_out, int out_size, void* d_ws, size_t ws_size,
                              hipStream_t stream) {
    const float* user  = (const float*)d_in[0];
    const float* prod  = (const float*)d_in[1];
    const float* word  = (const float*)d_in[2];
    const float* brand = (const float*)d_in[3];
    const float* cat   = (const float*)d_in[4];
    const float* rprod = (const float*)d_in[5];

    Params p;
    p.rel_vecs   = (const float*)d_in[6];
    p.batch_idxs = (const int*)d_in[15];
    p.neg_idxs   = (const int*)d_in[16];
    p.out        = (float*)d_out;

    p.rel[0] = {user, prod,  (const float*)d_in[7],  0, 1};  // purchase
    p.rel[1] = {user, word,  (const float*)d_in[8],  0, 2};  // mentions
    p.rel[2] = {prod, word,  (const float*)d_in[9],  1, 2};  // describe
    p.rel[3] = {prod, brand, (const float*)d_in[10], 1, 3};  // produced
    p.rel[4] = {prod, cat,   (const float*)d_in[11], 1, 4};  // belongs
    p.rel[5] = {prod, rprod, (const float*)d_in[12], 1, 5};  // also_bought
    p.rel[6] = {prod, rprod, (const float*)d_in[13], 1, 6};  // also_viewed
    p.rel[7] = {prod, rprod, (const float*)d_in[14], 1, 7};  // together

    hipMemsetAsync(d_out, 0, sizeof(float), stream);
    ke_kernel<<<1024, 256, 0, stream>>>(p);
}

// Round 3
// 152.034 us; speedup vs baseline: 1.0116x; 1.0116x over previous
//
#include <hip/hip_runtime.h>

// KnowledgeEmbedding loss via bf16 MFMA GEMM, single phase.
// R14: coalescing attack. R13 falsified occupancy (2->4 blocks/CU: no change),
// LDS conflicts, and same-address atomics (512 vs 1024: no change). Remaining
// suspect: uncoalesced gather (1 thread = 1 row -> 64 line-requests per wave
// vmem instr; 400 GB/s effective on a cold-L2 scatter).
// Changes:
//  - 8 lanes per row staging: lane g loads float4 {g,g+8,g+16} -> each 8-lane
//    group reads one contiguous 128B line -> <=8 transactions/instr (8x fewer).
//  - BN=256 (nb merged): grid 512 = 8 rel x 64 rowblocks; each head row
//    gathered exactly once (was 2x), neg re-reads halved. LDS 66.5 KB ->
//    2 blocks/CU (occupancy proven irrelevant in R13).
//  - Pos term: 4 lanes/row, lane p reads float4 j=p+4t (contiguous 64B/group).
// Kept: PITCH=104 (conflict-free odd-mod-32 stride), bias folded at k=100
// (A=bias, B=1.0), zero-B k-tail trick, XCD-affine rel = bid&7 (neg-table L2
// reuse), same-address atomic finish (exonerated).

#define EMBED   100
#define BATCH   4096
#define NUM_NEG 256
#define BM      64
#define BN      256
#define PITCH   104   // shorts per row = 208 B = 52 dwords (odd mod 32 banks)

typedef __attribute__((ext_vector_type(8))) short s8;
typedef __attribute__((ext_vector_type(4))) short s4;
typedef __attribute__((ext_vector_type(4))) float f4;

struct RelP {
    const float* head;
    const float* tail;
    const float* bias;
    int hc, tc;
};

struct Params {
    RelP rel[8];
    const float* rel_vecs;
    const int*   batch_idxs;
    const int*   neg_idxs;
    float*       out;
};

__device__ __forceinline__ float softplus_f(float x) {
    float e = __expf(-fabsf(x));
    return fmaxf(x, 0.0f) + __logf(1.0f + e);
}

__device__ __forceinline__ unsigned short bf16_rne(float f) {
    unsigned u = __float_as_uint(f);
    u += 0x7FFFu + ((u >> 16) & 1u);
    return (unsigned short)(u >> 16);
}

__device__ __forceinline__ float bf16_to_f(short s) {
    return __uint_as_float(((unsigned)(unsigned short)s) << 16);
}

__device__ __forceinline__ s4 pack4(float4 f) {
    s4 v = { (short)bf16_rne(f.x), (short)bf16_rne(f.y),
             (short)bf16_rne(f.z), (short)bf16_rne(f.w) };
    return v;
}

__launch_bounds__(256, 2)
__global__ void ke_kernel(Params p) {
    // grid: 512. bid&7 = rel (XCD-affine under %8 round-robin dispatch).
    const int bid = blockIdx.x;
    const int r   = bid & 7;
    const int rb  = bid >> 3;            // rowblock 0..63 (64 rows each)
    const int tid = threadIdx.x;

    __shared__ __align__(16) short As[BM * PITCH];   // 13312 B
    __shared__ __align__(16) short Bs[BN * PITCH];   // 53248 B -> total 66560 B

    const RelP rp = p.rel[r];

    const int g    = tid & 7;            // lane within row-group (0..7)
    const int rloc = tid >> 3;           // row slot within pass (0..31)

    // ---- A staging: 64 rows, 2 passes, 8 lanes/row (coalesced 128B/group) ----
    const float4* rv4 = (const float4*)(p.rel_vecs + r * EMBED);
#pragma unroll
    for (int pass = 0; pass < 2; ++pass) {
        const int row  = pass * 32 + rloc;
        const int grow = rb * BM + row;
        const int h = p.batch_idxs[grow * 8 + rp.hc];
        const float4* s4p = (const float4*)(rp.head + (size_t)h * EMBED);
        short* dst = As + row * PITCH;
#pragma unroll
        for (int t = 0; t < 3; ++t) {
            const int j = g + 8 * t;     // 0..23
            float4 f = s4p[j];
            const float4 a = rv4[j];
            f.x += a.x; f.y += a.y; f.z += a.z; f.w += a.w;
            *(s4*)(dst + 4 * j) = pack4(f);
        }
        if (g == 0) {                    // floats 96..99 + bias@100 + zeros
            const int ti = p.batch_idxs[grow * 8 + rp.tc];
            const unsigned short extra = bf16_rne(rp.bias[ti]);
            float4 f = s4p[24];
            const float4 a = rv4[24];
            f.x += a.x; f.y += a.y; f.z += a.z; f.w += a.w;
            s8 v = { (short)bf16_rne(f.x), (short)bf16_rne(f.y),
                     (short)bf16_rne(f.z), (short)bf16_rne(f.w),
                     (short)extra, 0, 0, 0 };
            *(s8*)(dst + 96) = v;
        }
    }

    // ---- B staging: 256 rows, 8 passes, 8 lanes/row ----
#pragma unroll
    for (int pass = 0; pass < 8; ++pass) {
        const int row = pass * 32 + rloc;
        const int n = p.neg_idxs[r * NUM_NEG + row];
        const float4* s4p = (const float4*)(rp.tail + (size_t)n * EMBED);
        short* dst = Bs + row * PITCH;
#pragma unroll
        for (int t = 0; t < 3; ++t) {
            const int j = g + 8 * t;
            *(s4*)(dst + 4 * j) = pack4(s4p[j]);
        }
        if (g == 0) {                    // floats 96..99 + 1.0@100 (bias pass)
            float4 f = s4p[24];
            s8 v = { (short)bf16_rne(f.x), (short)bf16_rne(f.y),
                     (short)bf16_rne(f.z), (short)bf16_rne(f.w),
                     (short)0x3F80, 0, 0, 0 };
            *(s8*)(dst + 96) = v;
        }
    }

    // pos-term prep (issued before barrier): 4 threads/row, 64 rows
    const int prow_l = tid >> 2;         // 0..63
    const int pp     = tid & 3;
    const int pgrow  = rb * BM + prow_l;
    const int pt     = p.batch_idxs[pgrow * 8 + rp.tc];
    const float* ptail = rp.tail + (size_t)pt * EMBED;
    const float  pbias = rp.bias[pt];

    __syncthreads();

    // ---- MFMA: 4 waves as 2x2, wave tile 32 rows x 128 negs ----
    const int wave = tid >> 6;
    const int lane = tid & 63;
    const int li   = lane & 15;
    const int q    = lane >> 4;
    const int wm   = wave >> 1;          // row half (32 rows)
    const int wn   = wave & 1;           // neg half (128 negs)

    f4 acc[2][8];
#pragma unroll
    for (int i = 0; i < 2; ++i)
#pragma unroll
        for (int j = 0; j < 8; ++j)
            acc[i][j] = (f4){0.f, 0.f, 0.f, 0.f};

    const short* Ab = As + (wm * 32 + li) * PITCH;
    const short* Bb = Bs + (wn * 128 + li) * PITCH;

#pragma unroll
    for (int s = 0; s < 3; ++s) {        // k = 0..95, chunks q+4s all real
        const int co = 8 * (q + 4 * s);
        s8 a[2], b[8];
        a[0] = *(const s8*)(Ab + co);
        a[1] = *(const s8*)(Ab + 16 * PITCH + co);
#pragma unroll
        for (int j = 0; j < 8; ++j)
            b[j] = *(const s8*)(Bb + j * 16 * PITCH + co);
#pragma unroll
        for (int i = 0; i < 2; ++i)
#pragma unroll
            for (int j = 0; j < 8; ++j)
                acc[i][j] = __builtin_amdgcn_mfma_f32_16x16x32_bf16(a[i], b[j], acc[i][j], 0, 0, 0);
    }
    {   // s=3: k=96..127. Only q==0 (chunk 12) real; zero B for q>=1 so the
        // garbage A broadcast contributes exactly 0.
        const s8 z = {0, 0, 0, 0, 0, 0, 0, 0};
        s8 a[2], b[8];
        a[0] = *(const s8*)(Ab + 96);
        a[1] = *(const s8*)(Ab + 16 * PITCH + 96);
#pragma unroll
        for (int j = 0; j < 8; ++j) {
            b[j] = *(const s8*)(Bb + j * 16 * PITCH + 96);
            b[j] = q ? z : b[j];
        }
#pragma unroll
        for (int i = 0; i < 2; ++i)
#pragma unroll
            for (int j = 0; j < 8; ++j)
                acc[i][j] = __builtin_amdgcn_mfma_f32_16x16x32_bf16(a[i], b[j], acc[i][j], 0, 0, 0);
    }

    // ---- epilogue: softplus-sum (bias folded into acc, layout-agnostic) ----
    float local = 0.0f;
#pragma unroll
    for (int i = 0; i < 2; ++i)
#pragma unroll
        for (int j = 0; j < 8; ++j) {
            local += softplus_f(acc[i][j].x);
            local += softplus_f(acc[i][j].y);
            local += softplus_f(acc[i][j].z);
            local += softplus_f(acc[i][j].w);
        }

    // ---- positive term: 4 lanes/row, lane p reads float4 j = p+4t (coalesced) ----
    {
        const short* exr = As + prow_l * PITCH;
        const float4* tv = (const float4*)ptail;
        float d0 = 0.f, d1 = 0.f, d2 = 0.f, d3 = 0.f;
#pragma unroll
        for (int t = 0; t < 6; ++t) {
            const int j = pp + 4 * t;    // 0..23
            const s4 e = *(const s4*)(exr + 4 * j);
            const float4 t0 = tv[j];
            d0 = fmaf(bf16_to_f(e.x), t0.x, d0);
            d1 = fmaf(bf16_to_f(e.y), t0.y, d1);
            d2 = fmaf(bf16_to_f(e.z), t0.z, d2);
            d3 = fmaf(bf16_to_f(e.w), t0.w, d3);
        }
        if (pp == 0) {                   // j=24: floats 96..99
            const s4 e = *(const s4*)(exr + 96);
            const float4 t0 = tv[24];
            d0 = fmaf(bf16_to_f(e.x), t0.x, d0);
            d1 = fmaf(bf16_to_f(e.y), t0.y, d1);
            d2 = fmaf(bf16_to_f(e.z), t0.z, d2);
            d3 = fmaf(bf16_to_f(e.w), t0.w, d3);
        }
        float d = (d0 + d1) + (d2 + d3);
        d += __shfl_xor(d, 1, 64);
        d += __shfl_xor(d, 2, 64);       // 4-lane group holds full dot
        if (pp == 0) local += softplus_f(-(d + pbias));
    }

    // ---- reduction ----
#pragma unroll
    for (int off = 32; off > 0; off >>= 1)
        local += __shfl_down(local, off, 64);

    __syncthreads();                     // all As/Bs reads done -> safe to alias
    float* wsum = (float*)Bs;
    if ((tid & 63) == 0) wsum[tid >> 6] = local;
    __syncthreads();
    if (tid == 0) {
        const float s = (wsum[0] + wsum[1]) + (wsum[2] + wsum[3]);
        atomicAdd(p.out, s * (1.0f / BATCH));
    }
}

extern "C" void kernel_launch(void* const* d_in, const int* in_sizes, int n_in,
                              void* d_out, int out_size, void* d_ws, size_t ws_size,
                              hipStream_t stream) {
    const float* user  = (const float*)d_in[0];
    const float* prod  = (const float*)d_in[1];
    const float* word  = (const float*)d_in[2];
    const float* brand = (const float*)d_in[3];
    const float* cat   = (const float*)d_in[4];
    const float* rprod = (const float*)d_in[5];

    Params p;
    p.rel_vecs   = (const float*)d_in[6];
    p.batch_idxs = (const int*)d_in[15];
    p.neg_idxs   = (const int*)d_in[16];
    p.out        = (float*)d_out;

    p.rel[0] = {user, prod,  (const float*)d_in[7],  0, 1};  // purchase
    p.rel[1] = {user, word,  (const float*)d_in[8],  0, 2};  // mentions
    p.rel[2] = {prod, word,  (const float*)d_in[9],  1, 2};  // describe
    p.rel[3] = {prod, brand, (const float*)d_in[10], 1, 3};  // produced
    p.rel[4] = {prod, cat,   (const float*)d_in[11], 1, 4};  // belongs
    p.rel[5] = {prod, rprod, (const float*)d_in[12], 1, 5};  // also_bought
    p.rel[6] = {prod, rprod, (const float*)d_in[13], 1, 6};  // also_viewed
    p.rel[7] = {prod, rprod, (const float*)d_in[14], 1, 7};  // together

    hipMemsetAsync(d_out, 0, sizeof(float), stream);
    ke_kernel<<<512, 256, 0, stream>>>(p);
}